// Round 2
// baseline (242.919 us; speedup 1.0000x reference)
//
#include <hip/hip_runtime.h>

#define M_MEANS 256

typedef float f32x4 __attribute__((ext_vector_type(4)));

// One wave (64 lanes) per output row. Lane l owns means[4l..4l+3] in registers.
// Per row: compute |means - t|, wave-argmin with first-index tie-break, then
// each lane writes one float4 of the row (zero except the winning column).
__global__ __launch_bounds__(256) void TemperatureModel_81767587381683_kernel(
    const float* __restrict__ target,
    const float* __restrict__ means,
    float* __restrict__ out,
    int N)
{
    const int lane = threadIdx.x & 63;
    const int waveInBlock = threadIdx.x >> 6;
    const int wavesPerBlock = blockDim.x >> 6;
    const long long waveId = (long long)blockIdx.x * wavesPerBlock + waveInBlock;
    const long long numWaves = (long long)gridDim.x * wavesPerBlock;

    // Load this lane's 4 means once (16B coalesced; means = 1 KiB total, L2-resident).
    const f32x4 m4 = *reinterpret_cast<const f32x4*>(means + 4 * lane);
    const int cbase = 4 * lane;

    for (long long row = waveId; row < N; row += numWaves) {
        const float t = target[row];

        // Lane-local argmin over 4 candidates; strict '<' keeps lowest index on ties.
        float d0 = fabsf(m4.x - t);
        float d1 = fabsf(m4.y - t);
        float d2 = fabsf(m4.z - t);
        float d3 = fabsf(m4.w - t);

        float bd = d0; int bi = cbase + 0; float bv = m4.x;
        if (d1 < bd) { bd = d1; bi = cbase + 1; bv = m4.y; }
        if (d2 < bd) { bd = d2; bi = cbase + 2; bv = m4.z; }
        if (d3 < bd) { bd = d3; bi = cbase + 3; bv = m4.w; }

        // 64-lane butterfly argmin; tie-break to the smaller index (jnp.argmin semantics).
        #pragma unroll
        for (int off = 32; off >= 1; off >>= 1) {
            const float od = __shfl_xor(bd, off);
            const int   oi = __shfl_xor(bi, off);
            const float ov = __shfl_xor(bv, off);
            if (od < bd || (od == bd && oi < bi)) { bd = od; bi = oi; bv = ov; }
        }
        // All lanes now agree on (bi, bv).

        f32x4 o;
        o.x = (cbase + 0 == bi) ? bv : 0.0f;
        o.y = (cbase + 1 == bi) ? bv : 0.0f;
        o.z = (cbase + 2 == bi) ? bv : 0.0f;
        o.w = (cbase + 3 == bi) ? bv : 0.0f;

        // Streaming store: 1 GiB output is write-once, never re-read by us.
        f32x4* dst = reinterpret_cast<f32x4*>(out + (size_t)row * M_MEANS + cbase);
        __builtin_nontemporal_store(o, dst);
    }
}

extern "C" void kernel_launch(void* const* d_in, const int* in_sizes, int n_in,
                              void* d_out, int out_size, void* d_ws, size_t ws_size,
                              hipStream_t stream) {
    const float* target = (const float*)d_in[0];
    const float* means  = (const float*)d_in[1];
    float* out = (float*)d_out;
    const int N = in_sizes[0];  // 1,048,576

    // 2048 blocks x 256 threads = 8192 waves = full residency (32 waves/CU x 256 CU).
    dim3 grid(2048), block(256);
    hipLaunchKernelGGL(TemperatureModel_81767587381683_kernel, grid, block, 0, stream,
                       target, means, out, N);
}

// Round 3
// 207.107 us; speedup vs baseline: 1.1729x; 1.1729x over previous
//
#include <hip/hip_runtime.h>

#define M_MEANS 256

typedef float f32x4 __attribute__((ext_vector_type(4)));

// Block = 256 threads (4 waves). Per 256-row chunk:
//   Phase A: thread t computes the 256-way argmin for row chunkBase+t,
//            reading means as broadcast f32x4 from LDS (conflict-free).
//            4 independent accumulator chains (contiguous quarters) merged
//            in index order -> first-index tie-break preserved, 4x ILP.
//   Phase B: (idx,val) transposed through LDS; each wave writes 64 rows,
//            one coalesced 1 KiB store per row (only winning column nonzero).
__global__ __launch_bounds__(256) void TemperatureModel_81767587381683_kernel(
    const float* __restrict__ target,
    const float* __restrict__ means,
    float* __restrict__ out,
    int N)
{
    __shared__ __align__(16) float sMeans[M_MEANS];
    __shared__ float sVal[256];
    __shared__ int   sIdx[256];

    const int tid  = threadIdx.x;
    const int lane = tid & 63;
    const int wave = tid >> 6;
    const int cbase = 4 * lane;

    sMeans[tid] = means[tid];
    __syncthreads();

    const int numChunks = N >> 8;  // N is a multiple of 256 (N = 2^20)

    for (int chunk = blockIdx.x; chunk < numChunks; chunk += gridDim.x) {
        const int rowBase = chunk << 8;

        // ---- Phase A: per-thread argmin over 256 means ----
        const float t = target[rowBase + tid];

        float bd0 = 3.4e38f, bd1 = 3.4e38f, bd2 = 3.4e38f, bd3 = 3.4e38f;
        int   bi0 = 0,       bi1 = 64,      bi2 = 128,     bi3 = 192;

        #pragma unroll 4
        for (int k = 0; k < 64; k += 4) {
            const f32x4 m0 = *reinterpret_cast<const f32x4*>(&sMeans[k]);
            const f32x4 m1 = *reinterpret_cast<const f32x4*>(&sMeans[64 + k]);
            const f32x4 m2 = *reinterpret_cast<const f32x4*>(&sMeans[128 + k]);
            const f32x4 m3 = *reinterpret_cast<const f32x4*>(&sMeans[192 + k]);

            #pragma unroll
            for (int j = 0; j < 4; ++j) {
                const float d0 = fabsf(m0[j] - t);
                const float d1 = fabsf(m1[j] - t);
                const float d2 = fabsf(m2[j] - t);
                const float d3 = fabsf(m3[j] - t);
                if (d0 < bd0) { bd0 = d0; bi0 = k + j; }
                if (d1 < bd1) { bd1 = d1; bi1 = 64 + k + j; }
                if (d2 < bd2) { bd2 = d2; bi2 = 128 + k + j; }
                if (d3 < bd3) { bd3 = d3; bi3 = 192 + k + j; }
            }
        }
        // Merge quarters in ascending index order; strict '<' keeps lowest index.
        float bd = bd0; int bi = bi0;
        if (bd1 < bd) { bd = bd1; bi = bi1; }
        if (bd2 < bd) { bd = bd2; bi = bi2; }
        if (bd3 < bd) { bd = bd3; bi = bi3; }

        sVal[tid] = sMeans[bi];
        sIdx[tid] = bi;
        __syncthreads();

        // ---- Phase B: each wave writes its 64 rows, 1 KiB coalesced per row ----
        const int rfirst = wave << 6;
        float* basep = out + (size_t)(rowBase + rfirst) * M_MEANS;

        #pragma unroll 4
        for (int j = 0; j < 64; ++j) {
            const int   wbi = sIdx[rfirst + j];   // broadcast LDS read
            const float wbv = sVal[rfirst + j];   // broadcast LDS read
            f32x4 o;
            o.x = (cbase + 0 == wbi) ? wbv : 0.0f;
            o.y = (cbase + 1 == wbi) ? wbv : 0.0f;
            o.z = (cbase + 2 == wbi) ? wbv : 0.0f;
            o.w = (cbase + 3 == wbi) ? wbv : 0.0f;
            *reinterpret_cast<f32x4*>(basep + (size_t)j * M_MEANS + cbase) = o;
        }
        __syncthreads();  // protect sVal/sIdx before next chunk overwrites
    }
}

extern "C" void kernel_launch(void* const* d_in, const int* in_sizes, int n_in,
                              void* d_out, int out_size, void* d_ws, size_t ws_size,
                              hipStream_t stream) {
    const float* target = (const float*)d_in[0];
    const float* means  = (const float*)d_in[1];
    float* out = (float*)d_out;
    const int N = in_sizes[0];  // 1,048,576

    // 2048 blocks x 256 threads = 8 blocks/CU = 32 waves/CU (full residency);
    // each block handles 2 chunks of 256 rows.
    dim3 grid(2048), block(256);
    hipLaunchKernelGGL(TemperatureModel_81767587381683_kernel, grid, block, 0, stream,
                       target, means, out, N);
}

// Round 4
// 203.323 us; speedup vs baseline: 1.1947x; 1.0186x over previous
//
#include <hip/hip_runtime.h>

#define M_MEANS 256

typedef float f32x4 __attribute__((ext_vector_type(4)));

// Barrier-free main loop: each wave owns 64-row groups end-to-end.
//  Phase A: lane l computes the 256-way argmin for its row (means broadcast
//           from LDS, conflict-free; 4 independent chains merged in index
//           order -> first-index tie-break, 4x ILP).
//  Phase B: row j's (idx,val) lives in lane j of this wave -> v_readlane
//           broadcast (no LDS, no __syncthreads); wave writes 64 rows, one
//           coalesced 1 KiB store each. No barriers => waves desynchronize
//           and compute overlaps other waves' store drain.
__global__ __launch_bounds__(256) void TemperatureModel_81767587381683_kernel(
    const float* __restrict__ target,
    const float* __restrict__ means,
    float* __restrict__ out,
    int N)
{
    __shared__ __align__(16) float sMeans[M_MEANS];

    const int tid  = threadIdx.x;
    const int lane = tid & 63;
    const int wave = tid >> 6;
    const int cbase = 4 * lane;

    sMeans[tid] = means[tid];
    __syncthreads();  // the only barrier: means staging

    const int numGroups = N >> 6;                    // 64 rows per group
    const int waveId   = blockIdx.x * 4 + wave;
    const int numWaves = gridDim.x * 4;

    for (int g = waveId; g < numGroups; g += numWaves) {
        // ---- Phase A: this lane's row argmin over 256 means ----
        const float t = target[(g << 6) + lane];

        float bd0 = 3.4e38f, bd1 = 3.4e38f, bd2 = 3.4e38f, bd3 = 3.4e38f;
        int   bi0 = 0,       bi1 = 64,      bi2 = 128,     bi3 = 192;

        #pragma unroll 4
        for (int k = 0; k < 64; k += 4) {
            const f32x4 m0 = *reinterpret_cast<const f32x4*>(&sMeans[k]);
            const f32x4 m1 = *reinterpret_cast<const f32x4*>(&sMeans[64 + k]);
            const f32x4 m2 = *reinterpret_cast<const f32x4*>(&sMeans[128 + k]);
            const f32x4 m3 = *reinterpret_cast<const f32x4*>(&sMeans[192 + k]);

            #pragma unroll
            for (int j = 0; j < 4; ++j) {
                const float d0 = fabsf(m0[j] - t);
                const float d1 = fabsf(m1[j] - t);
                const float d2 = fabsf(m2[j] - t);
                const float d3 = fabsf(m3[j] - t);
                if (d0 < bd0) { bd0 = d0; bi0 = k + j; }
                if (d1 < bd1) { bd1 = d1; bi1 = 64 + k + j; }
                if (d2 < bd2) { bd2 = d2; bi2 = 128 + k + j; }
                if (d3 < bd3) { bd3 = d3; bi3 = 192 + k + j; }
            }
        }
        // Merge quarters in ascending index order; strict '<' keeps lowest index.
        float bd = bd0; int bi = bi0;
        if (bd1 < bd) { bd = bd1; bi = bi1; }
        if (bd2 < bd) { bd = bd2; bi = bi2; }
        if (bd3 < bd) { bd = bd3; bi = bi3; }

        const float bv = sMeans[bi];  // per-lane gather, once per row

        // ---- Phase B: wave writes its 64 rows; readlane broadcast, no sync ----
        float* basep = out + (((size_t)g << 6) * M_MEANS) + cbase;
        const int bvbits = __float_as_int(bv);

        #pragma unroll 8
        for (int j = 0; j < 64; ++j) {
            const int   sbi = __builtin_amdgcn_readlane(bi, j);
            const float sbv = __int_as_float(__builtin_amdgcn_readlane(bvbits, j));
            f32x4 o;
            o.x = (cbase + 0 == sbi) ? sbv : 0.0f;
            o.y = (cbase + 1 == sbi) ? sbv : 0.0f;
            o.z = (cbase + 2 == sbi) ? sbv : 0.0f;
            o.w = (cbase + 3 == sbi) ? sbv : 0.0f;
            *reinterpret_cast<f32x4*>(basep + (size_t)j * M_MEANS) = o;
        }
    }
}

extern "C" void kernel_launch(void* const* d_in, const int* in_sizes, int n_in,
                              void* d_out, int out_size, void* d_ws, size_t ws_size,
                              hipStream_t stream) {
    const float* target = (const float*)d_in[0];
    const float* means  = (const float*)d_in[1];
    float* out = (float*)d_out;
    const int N = in_sizes[0];  // 1,048,576

    // 2048 blocks x 256 threads = 8192 waves = full residency; each wave
    // free-runs over 2 groups of 64 rows with no inter-wave coupling.
    dim3 grid(2048), block(256);
    hipLaunchKernelGGL(TemperatureModel_81767587381683_kernel, grid, block, 0, stream,
                       target, means, out, N);
}

// Round 5
// 202.046 us; speedup vs baseline: 1.2023x; 1.0063x over previous
//
#include <hip/hip_runtime.h>

#define M_MEANS 256

typedef float f32x4 __attribute__((ext_vector_type(4)));

// Software-pipelined, barrier-free: each wave owns 64-row groups.
//  Prologue: argmin for first group (lane = one row; means broadcast from LDS;
//            4 index-ordered chains -> exact first-index tie-break).
//  Main loop: the 64-iteration store loop of group g ALSO computes the argmin
//            of group g+stride (4 means per iteration), so stores issue
//            continuously and the A-phase HBM bubble disappears.
//  Epilogue: plain store loop for the final group (no dead A work).
__global__ __launch_bounds__(256) void TemperatureModel_81767587381683_kernel(
    const float* __restrict__ target,
    const float* __restrict__ means,
    float* __restrict__ out,
    int N)
{
    __shared__ __align__(16) float sMeans[M_MEANS];

    const int tid  = threadIdx.x;
    const int lane = tid & 63;
    const int wave = tid >> 6;
    const int cbase = 4 * lane;

    sMeans[tid] = means[tid];
    __syncthreads();  // only barrier: means staging

    const int numGroups = N >> 6;                // 64 rows per group
    const int waveId    = blockIdx.x * 4 + wave;
    const int numWaves  = gridDim.x * 4;
    if (waveId >= numGroups) return;

    // ---- Prologue: argmin for group g0 ----
    int g = waveId;
    int bi;
    float bv;
    {
        const float t = target[(g << 6) + lane];
        float bd0 = 3.4e38f, bd1 = 3.4e38f, bd2 = 3.4e38f, bd3 = 3.4e38f;
        int   bi0 = 0,       bi1 = 64,      bi2 = 128,     bi3 = 192;
        #pragma unroll 4
        for (int k = 0; k < 64; k += 4) {
            const f32x4 m0 = *reinterpret_cast<const f32x4*>(&sMeans[k]);
            const f32x4 m1 = *reinterpret_cast<const f32x4*>(&sMeans[64 + k]);
            const f32x4 m2 = *reinterpret_cast<const f32x4*>(&sMeans[128 + k]);
            const f32x4 m3 = *reinterpret_cast<const f32x4*>(&sMeans[192 + k]);
            #pragma unroll
            for (int j = 0; j < 4; ++j) {
                const float d0 = fabsf(m0[j] - t);
                const float d1 = fabsf(m1[j] - t);
                const float d2 = fabsf(m2[j] - t);
                const float d3 = fabsf(m3[j] - t);
                if (d0 < bd0) { bd0 = d0; bi0 = k + j; }
                if (d1 < bd1) { bd1 = d1; bi1 = 64 + k + j; }
                if (d2 < bd2) { bd2 = d2; bi2 = 128 + k + j; }
                if (d3 < bd3) { bd3 = d3; bi3 = 192 + k + j; }
            }
        }
        float bd = bd0; bi = bi0;
        if (bd1 < bd) { bd = bd1; bi = bi1; }
        if (bd2 < bd) { bd = bd2; bi = bi2; }
        if (bd3 < bd) { bd = bd3; bi = bi3; }
        bv = sMeans[bi];
    }

    // ---- Main loop: stores of group g fused with argmin of group g+stride ----
    for (;;) {
        const int gn = g + numWaves;
        if (gn >= numGroups) break;

        const float tn = target[(gn << 6) + lane];  // issued early, hidden under stores

        float nbd0 = 3.4e38f, nbd1 = 3.4e38f, nbd2 = 3.4e38f, nbd3 = 3.4e38f;
        int   nbi0 = 0,       nbi1 = 64,      nbi2 = 128,     nbi3 = 192;

        float* basep = out + ((((size_t)g) << 6) * M_MEANS) + cbase;
        const int bvbits = __float_as_int(bv);

        #pragma unroll 4
        for (int j = 0; j < 64; ++j) {
            // B: store row j of group g (only winning column nonzero)
            const int   sbi = __builtin_amdgcn_readlane(bi, j);
            const float sbv = __int_as_float(__builtin_amdgcn_readlane(bvbits, j));
            const int ee = sbi - cbase;
            f32x4 o;
            o.x = (ee == 0) ? sbv : 0.0f;
            o.y = (ee == 1) ? sbv : 0.0f;
            o.z = (ee == 2) ? sbv : 0.0f;
            o.w = (ee == 3) ? sbv : 0.0f;
            *reinterpret_cast<f32x4*>(basep + (size_t)j * M_MEANS) = o;

            // A(next): one step of each of the 4 index-ordered chains
            const float d0 = fabsf(sMeans[j]       - tn);
            const float d1 = fabsf(sMeans[64 + j]  - tn);
            const float d2 = fabsf(sMeans[128 + j] - tn);
            const float d3 = fabsf(sMeans[192 + j] - tn);
            if (d0 < nbd0) { nbd0 = d0; nbi0 = j; }
            if (d1 < nbd1) { nbd1 = d1; nbi1 = 64 + j; }
            if (d2 < nbd2) { nbd2 = d2; nbi2 = 128 + j; }
            if (d3 < nbd3) { nbd3 = d3; nbi3 = 192 + j; }
        }

        // merge quarters in ascending index order (first-index tie-break)
        float nbd = nbd0; int nbi = nbi0;
        if (nbd1 < nbd) { nbd = nbd1; nbi = nbi1; }
        if (nbd2 < nbd) { nbd = nbd2; nbi = nbi2; }
        if (nbd3 < nbd) { nbd = nbd3; nbi = nbi3; }
        bi = nbi;
        bv = sMeans[nbi];
        g = gn;
    }

    // ---- Epilogue: plain store loop for the last group ----
    {
        float* basep = out + ((((size_t)g) << 6) * M_MEANS) + cbase;
        const int bvbits = __float_as_int(bv);
        #pragma unroll 4
        for (int j = 0; j < 64; ++j) {
            const int   sbi = __builtin_amdgcn_readlane(bi, j);
            const float sbv = __int_as_float(__builtin_amdgcn_readlane(bvbits, j));
            const int ee = sbi - cbase;
            f32x4 o;
            o.x = (ee == 0) ? sbv : 0.0f;
            o.y = (ee == 1) ? sbv : 0.0f;
            o.z = (ee == 2) ? sbv : 0.0f;
            o.w = (ee == 3) ? sbv : 0.0f;
            *reinterpret_cast<f32x4*>(basep + (size_t)j * M_MEANS) = o;
        }
    }
}

extern "C" void kernel_launch(void* const* d_in, const int* in_sizes, int n_in,
                              void* d_out, int out_size, void* d_ws, size_t ws_size,
                              hipStream_t stream) {
    const float* target = (const float*)d_in[0];
    const float* means  = (const float*)d_in[1];
    float* out = (float*)d_out;
    const int N = in_sizes[0];  // 1,048,576

    // 2048 blocks x 256 threads = 8192 waves = exactly full residency;
    // each wave: prologue argmin + 1 fused iteration + epilogue stores.
    dim3 grid(2048), block(256);
    hipLaunchKernelGGL(TemperatureModel_81767587381683_kernel, grid, block, 0, stream,
                       target, means, out, N);
}